// Round 1
// baseline (1623.769 us; speedup 1.0000x reference)
//
#include <hip/hip_runtime.h>
#include <math.h>

#define NN 50000
#define NE 800000
#define TDIM 100
#define EDIM 101

// cos(x) for fp32 x matching np.cos(float32) to ~1e-6:
// 2-term Cody-Waite reduction of x/(2pi) into [-0.5,0.5] revolutions,
// then hardware v_cos_f32 (input in revolutions).
__device__ __forceinline__ float ref_cosf(float x) {
  const float C1 = 0.15915494f;      // hi(1/2pi) = 10680707 * 2^-26
  const float C2 = 6.42063831e-9f;   // lo(1/2pi)
  float p = x * C1;
  float r = __fmaf_rn(x, C1, -p);    // exact product residual
  r = __fmaf_rn(x, C2, r);
  float n = rintf(p);
  float f = (p - n) + r;             // exact (both multiples of ulp, |f|<=0.5+eps)
  return __builtin_amdgcn_cosf(f);
}

// ---------------- projection GEMM: [NN,128] x [128,512] -> Q|K|V|S ----------
#define PBM 32
#define PBK 16
__global__ __launch_bounds__(256, 4) void k_proj(
    const float* __restrict__ x,
    const float* __restrict__ Wq, const float* __restrict__ bq,
    const float* __restrict__ Wk, const float* __restrict__ bk,
    const float* __restrict__ Wv, const float* __restrict__ bv,
    const float* __restrict__ Wskip, const float* __restrict__ bskip,
    float* __restrict__ Q, float* __restrict__ K2,
    float* __restrict__ V2, float* __restrict__ S2)
{
  __shared__ float a_s[PBK][PBM + 1];   // [k][row]
  __shared__ float b_s[PBK][512];
  const int tid = threadIdx.x;
  const int n0 = blockIdx.x * PBM;
  const int tr = tid >> 6;   // 0..3 (row group of 8)
  const int tc = tid & 63;   // col lane

  float acc[8][8];
#pragma unroll
  for (int r = 0; r < 8; ++r)
#pragma unroll
    for (int i = 0; i < 8; ++i) acc[r][i] = 0.f;

  for (int kt = 0; kt < 128; kt += PBK) {
    {
      int row = tid >> 3, k2 = (tid & 7) << 1;
      float2 v = make_float2(0.f, 0.f);
      if (n0 + row < NN) v = *(const float2*)&x[(size_t)(n0 + row) * 128 + kt + k2];
      a_s[k2][row] = v.x; a_s[k2 + 1][row] = v.y;
    }
#pragma unroll 4
    for (int i = 0; i < 32; ++i) {
      int idx = tid + (i << 8);
      int k = idx >> 9, o = idx & 511;
      const float* W = (o < 128) ? Wq : (o < 256) ? Wk : (o < 384) ? Wv : Wskip;
      b_s[k][o] = W[(kt + k) * 128 + (o & 127)];
    }
    __syncthreads();
#pragma unroll
    for (int k = 0; k < PBK; ++k) {
      float a[8], b[8];
#pragma unroll
      for (int r = 0; r < 8; ++r) a[r] = a_s[k][tr * 8 + r];
#pragma unroll
      for (int i = 0; i < 8; ++i) b[i] = b_s[k][tc + (i << 6)];
#pragma unroll
      for (int r = 0; r < 8; ++r)
#pragma unroll
        for (int i = 0; i < 8; ++i) acc[r][i] = fmaf(a[r], b[i], acc[r][i]);
    }
    __syncthreads();
  }

#pragma unroll
  for (int i = 0; i < 8; ++i) {
    int o = tc + (i << 6);
    int c = o & 127;
    const float* bias = (o < 128) ? bq : (o < 256) ? bk : (o < 384) ? bv : bskip;
    float* dst = (o < 128) ? Q : (o < 256) ? K2 : (o < 384) ? V2 : S2;
    float bb = bias[c];
#pragma unroll
    for (int r = 0; r < 8; ++r) {
      int row = n0 + tr * 8 + r;
      if (row < NN) dst[(size_t)row * 128 + c] = acc[r][i] + bb;
    }
  }
}

// ---------------- CSR build ----------------
__global__ void k_deg(const int* __restrict__ ei, int* __restrict__ deg) {
  int e = blockIdx.x * 256 + threadIdx.x;
  if (e < NE) atomicAdd(&deg[ei[NE + e]], 1);
}

__global__ __launch_bounds__(1024) void k_scan(const int* __restrict__ deg,
                                               int* __restrict__ off) {
  __shared__ int s[1024];
  int carry = 0;
  for (int base = 0; base < NN; base += 1024) {
    int i = base + threadIdx.x;
    int v = (i < NN) ? deg[i] : 0;
    s[threadIdx.x] = v;
    __syncthreads();
    for (int o = 1; o < 1024; o <<= 1) {
      int t = 0;
      if (threadIdx.x >= o) t = s[threadIdx.x - o];
      __syncthreads();
      if (threadIdx.x >= o) s[threadIdx.x] += t;
      __syncthreads();
    }
    int incl = s[threadIdx.x];
    if (i < NN) off[i] = carry + incl - v;   // exclusive
    int tot = s[1023];
    __syncthreads();
    carry += tot;
  }
  if (threadIdx.x == 0) off[NN] = carry;
}

__global__ void k_fill(const int* __restrict__ ei, const int* __restrict__ off,
                       int* __restrict__ cur, int* __restrict__ elist) {
  int e = blockIdx.x * 256 + threadIdx.x;
  if (e < NE) {
    int d = ei[NE + e];
    int p = atomicAdd(&cur[d], 1);
    elist[off[d] + p] = e;
  }
}

// ---------------- fused attention + epilogue: one wave per dst node ---------
__global__ __launch_bounds__(256, 3) void k_main(
    const float* __restrict__ Q, const float* __restrict__ K2,
    const float* __restrict__ V2, const float* __restrict__ S2,
    const float* __restrict__ Wt, const float* __restrict__ bt,
    const float* __restrict__ We,
    const float* __restrict__ gamma, const float* __restrict__ beta,
    const float* __restrict__ msg, const int* __restrict__ last_update,
    const int* __restrict__ ei, const int* __restrict__ tt,
    const int* __restrict__ off, const int* __restrict__ elist,
    float* __restrict__ out)
{
  __shared__ unsigned We_s[EDIM * 64];      // bf16x2 packed (ch 2l | 2l+1)
  __shared__ float Wt_s[TDIM], bt_s[TDIM];
  __shared__ float attr_s[4][16][104];      // per-wave, 16-edge batch, 16B-aligned rows

  for (int i = threadIdx.x; i < EDIM * 64; i += 256) {
    float2 w = ((const float2*)We)[i];
    unsigned ua = __float_as_uint(w.x), ub = __float_as_uint(w.y);
    unsigned ra = (ua + 0x7FFFu + ((ua >> 16) & 1u)) >> 16;            // RNE bf16
    unsigned rb = (ub + 0x7FFFu + ((ub >> 16) & 1u)) & 0xFFFF0000u;
    We_s[i] = (ra & 0xFFFFu) | rb;
  }
  if (threadIdx.x < TDIM) { Wt_s[threadIdx.x] = Wt[threadIdx.x]; bt_s[threadIdx.x] = bt[threadIdx.x]; }
  __syncthreads();

  const int wid = threadIdx.x >> 6, lane = threadIdx.x & 63;
  const int node = blockIdx.x * 4 + wid;
  if (node >= NN) return;

  const int o0 = off[node];
  const int deg = off[node + 1] - o0;
  float2 q = ((const float2*)Q)[node * 64 + lane];   // channels 2l, 2l+1; head = lane/16
  float m = -INFINITY, l = 0.f, acc0 = 0.f, acc1 = 0.f;
  float (*attrw)[104] = attr_s[wid];

  for (int cb = 0; cb < deg; cb += 16) {
    int cnt = deg - cb; if (cnt > 16) cnt = 16;

    // edge metadata: lanes 0..cnt-1
    float rel = 0.f, mg = 0.f; int srcl = 0;
    if (lane < cnt) {
      int eid = elist[o0 + cb + lane];
      srcl = ei[eid];
      mg = msg[eid];
      rel = (float)(last_update[srcl] - tt[eid]);
    }

    // edge_attr -> per-wave LDS (101 values per edge)
#pragma unroll
    for (int ed = 0; ed < 16; ++ed) {
      if (ed < cnt) {
        float rel_e = __shfl(rel, ed);
        float mg_e  = __shfl(mg, ed);
        attrw[ed][lane] = ref_cosf(__fmaf_rn(rel_e, Wt_s[lane], bt_s[lane]));
        int j2 = 64 + lane;
        if (j2 < TDIM)       attrw[ed][j2]   = ref_cosf(__fmaf_rn(rel_e, Wt_s[j2], bt_s[j2]));
        else if (j2 == TDIM) attrw[ed][TDIM] = mg_e;
      }
    }
    asm volatile("s_waitcnt lgkmcnt(0)" ::: "memory");

    // e = edge_attr @ We for 16 edges, channels (2l, 2l+1) per lane
    float e0[16], e1[16];
#pragma unroll
    for (int ed = 0; ed < 16; ++ed) { e0[ed] = 0.f; e1[ed] = 0.f; }
    for (int j4 = 0; j4 < TDIM; j4 += 4) {
      unsigned w0 = We_s[(j4 + 0) * 64 + lane];
      unsigned w1 = We_s[(j4 + 1) * 64 + lane];
      unsigned w2 = We_s[(j4 + 2) * 64 + lane];
      unsigned w3 = We_s[(j4 + 3) * 64 + lane];
      float w0x = __uint_as_float(w0 << 16), w0y = __uint_as_float(w0 & 0xFFFF0000u);
      float w1x = __uint_as_float(w1 << 16), w1y = __uint_as_float(w1 & 0xFFFF0000u);
      float w2x = __uint_as_float(w2 << 16), w2y = __uint_as_float(w2 & 0xFFFF0000u);
      float w3x = __uint_as_float(w3 << 16), w3y = __uint_as_float(w3 & 0xFFFF0000u);
#pragma unroll
      for (int ed = 0; ed < 16; ++ed) {
        float4 a = *(const float4*)&attrw[ed][j4];
        e0[ed] = fmaf(a.x, w0x, e0[ed]); e1[ed] = fmaf(a.x, w0y, e1[ed]);
        e0[ed] = fmaf(a.y, w1x, e0[ed]); e1[ed] = fmaf(a.y, w1y, e1[ed]);
        e0[ed] = fmaf(a.z, w2x, e0[ed]); e1[ed] = fmaf(a.z, w2y, e1[ed]);
        e0[ed] = fmaf(a.w, w3x, e0[ed]); e1[ed] = fmaf(a.w, w3y, e1[ed]);
      }
    }
    {   // j = 100 (raw message channel)
      unsigned w = We_s[TDIM * 64 + lane];
      float wx = __uint_as_float(w << 16), wy = __uint_as_float(w & 0xFFFF0000u);
#pragma unroll
      for (int ed = 0; ed < 16; ++ed) {
        float a = attrw[ed][TDIM];
        e0[ed] = fmaf(a, wx, e0[ed]); e1[ed] = fmaf(a, wy, e1[ed]);
      }
    }

    // alpha + v for each edge
    float al[16], vx0[16], vy0[16];
#pragma unroll
    for (int ed = 0; ed < 16; ++ed) {
      if (ed < cnt) {
        int se = __shfl(srcl, ed);
        float2 kk = ((const float2*)K2)[se * 64 + lane];
        float kj0 = kk.x + e0[ed], kj1 = kk.y + e1[ed];
        float p = q.x * kj0 + q.y * kj1;
        p += __shfl_xor(p, 1); p += __shfl_xor(p, 2);
        p += __shfl_xor(p, 4); p += __shfl_xor(p, 8);   // 16-lane head reduce
        al[ed] = p * 0.17677669529663689f;               // 1/sqrt(32)
        float2 vv = ((const float2*)V2)[se * 64 + lane];
        vx0[ed] = vv.x + e0[ed]; vy0[ed] = vv.y + e1[ed];
      }
    }

    // online softmax update
    float cm = -INFINITY;
#pragma unroll
    for (int ed = 0; ed < 16; ++ed) if (ed < cnt) cm = fmaxf(cm, al[ed]);
    float nm = fmaxf(m, cm);
    float sc = __expf(m - nm);   // m=-inf -> 0
    l *= sc; acc0 *= sc; acc1 *= sc;
#pragma unroll
    for (int ed = 0; ed < 16; ++ed) {
      if (ed < cnt) {
        float w = __expf(al[ed] - nm);
        l += w;
        acc0 = fmaf(w, vx0[ed], acc0);
        acc1 = fmaf(w, vy0[ed], acc1);
      }
    }
    m = nm;
  }

  // epilogue: agg/den + skip, relu, layernorm (wave-wide over 128 channels)
  float inv = 1.f / (l + 1e-16f);
  float2 s2 = ((const float2*)S2)[node * 64 + lane];
  float r0 = fmaxf(fmaf(acc0, inv, s2.x), 0.f);
  float r1 = fmaxf(fmaf(acc1, inv, s2.y), 0.f);

  float sum = r0 + r1;
#pragma unroll
  for (int o = 1; o < 64; o <<= 1) sum += __shfl_xor(sum, o);
  float mu = sum * 0.0078125f;
  float d0 = r0 - mu, d1 = r1 - mu;
  float vs = d0 * d0 + d1 * d1;
#pragma unroll
  for (int o = 1; o < 64; o <<= 1) vs += __shfl_xor(vs, o);
  float rstd = rsqrtf(vs * 0.0078125f + 1e-5f);
  float2 g = ((const float2*)gamma)[lane], b = ((const float2*)beta)[lane];
  ((float2*)out)[node * 64 + lane] =
      make_float2(d0 * rstd * g.x + b.x, d1 * rstd * g.y + b.y);
}

// ---------------- launch ----------------
// ws layout (bytes):
//   Q 0 | K 25.6e6 | V 51.2e6 | S 76.8e6 | deg 102.4e6 | cur 102.6e6
//   off 102.8e6 (N+1 ints, padded) | elist 103,000,064 | total 106,200,064
extern "C" void kernel_launch(void* const* d_in, const int* in_sizes, int n_in,
                              void* d_out, int out_size, void* d_ws, size_t ws_size,
                              hipStream_t stream)
{
  (void)in_sizes; (void)n_in; (void)out_size;
  if (ws_size < 106200064u) return;  // insufficient scratch -> fail visibly

  const float* x     = (const float*)d_in[0];
  const float* msg   = (const float*)d_in[1];
  const float* Wt    = (const float*)d_in[2];
  const float* bt    = (const float*)d_in[3];
  const float* Wq    = (const float*)d_in[4];
  const float* bq    = (const float*)d_in[5];
  const float* Wk    = (const float*)d_in[6];
  const float* bk    = (const float*)d_in[7];
  const float* Wv    = (const float*)d_in[8];
  const float* bv    = (const float*)d_in[9];
  const float* We    = (const float*)d_in[10];
  const float* Wskip = (const float*)d_in[11];
  const float* bskip = (const float*)d_in[12];
  const float* gamma = (const float*)d_in[13];
  const float* beta  = (const float*)d_in[14];
  const int* last_update = (const int*)d_in[15];
  const int* ei    = (const int*)d_in[16];
  const int* tt    = (const int*)d_in[17];

  char* ws = (char*)d_ws;
  float* Q    = (float*)(ws);
  float* K2   = (float*)(ws + 25600000);
  float* V2   = (float*)(ws + 51200000);
  float* S2   = (float*)(ws + 76800000);
  int* deg    = (int*)(ws + 102400000);
  int* cur    = (int*)(ws + 102600000);
  int* off    = (int*)(ws + 102800000);
  int* elist  = (int*)(ws + 103000064);

  hipMemsetAsync(deg, 0, 400000, stream);              // deg + cur (contiguous)
  k_deg <<<(NE + 255) / 256, 256, 0, stream>>>(ei, deg);
  k_scan<<<1, 1024, 0, stream>>>(deg, off);
  k_fill<<<(NE + 255) / 256, 256, 0, stream>>>(ei, off, cur, elist);
  k_proj<<<(NN + PBM - 1) / PBM, 256, 0, stream>>>(x, Wq, bq, Wk, bk, Wv, bv,
                                                   Wskip, bskip, Q, K2, V2, S2);
  k_main<<<(NN + 3) / 4, 256, 0, stream>>>(Q, K2, V2, S2, Wt, bt, We, gamma, beta,
                                           msg, last_update, ei, tt, off, elist,
                                           (float*)d_out);
}

// Round 2
// 945.208 us; speedup vs baseline: 1.7179x; 1.7179x over previous
//
#include <hip/hip_runtime.h>
#include <math.h>

#define NN 50000
#define NE 800000
#define TDIM 100
#define EDIM 101

// cos(x) for fp32 x matching np.cos(float32) to ~1e-6:
// 2-term Cody-Waite reduction of x/(2pi) into [-0.5,0.5] revolutions,
// then hardware v_cos_f32 (input in revolutions).
__device__ __forceinline__ float ref_cosf(float x) {
  const float C1 = 0.15915494f;      // hi(1/2pi) = 10680707 * 2^-26
  const float C2 = 6.42063831e-9f;   // lo(1/2pi)
  float p = x * C1;
  float r = __fmaf_rn(x, C1, -p);    // exact product residual
  r = __fmaf_rn(x, C2, r);
  float n = rintf(p);
  float f = (p - n) + r;
  return __builtin_amdgcn_cosf(f);
}

// ---------------- projection GEMM: [NN,128] x [128,512] -> Q|K|V|S ----------
// 64x64 block tile, 4x4 per-thread micro-tile (16 accs -> no spill).
// grid = (8 col-tiles, 782 row-tiles); col-tile fastest for x L2 reuse.
#define PBK 16
__global__ void k_proj(
    const float* __restrict__ x,
    const float* __restrict__ Wq, const float* __restrict__ bq,
    const float* __restrict__ Wk, const float* __restrict__ bk,
    const float* __restrict__ Wv, const float* __restrict__ bv,
    const float* __restrict__ Wskip, const float* __restrict__ bskip,
    float* __restrict__ Q, float* __restrict__ K2,
    float* __restrict__ V2, float* __restrict__ S2)
{
  __shared__ float a_s[PBK][68];   // [k][row], 272B rows (16B-aligned)
  __shared__ float b_s[PBK][64];   // [k][col]

  const int tid = threadIdx.x;
  const int cy = blockIdx.x;              // 0..7: which 64-col slice of 512
  const int n0 = blockIdx.y * 64;

  const float* W    = (cy < 2) ? Wq : (cy < 4) ? Wk : (cy < 6) ? Wv : Wskip;
  const float* bias = (cy < 2) ? bq : (cy < 4) ? bk : (cy < 6) ? bv : bskip;
  float* dst        = (cy < 2) ? Q  : (cy < 4) ? K2 : (cy < 6) ? V2 : S2;
  const int cb = (cy & 1) * 64;

  const int ty = tid >> 4, tx = tid & 15;  // 16x16 thread grid, 4x4 each
  const int lrow = tid >> 2, lk4 = (tid & 3) << 2;   // a-stage: float4 per thread
  const int lc = tid & 63, lk0 = tid >> 6;           // b-stage

  float acc[4][4];
#pragma unroll
  for (int r = 0; r < 4; ++r)
#pragma unroll
    for (int j = 0; j < 4; ++j) acc[r][j] = 0.f;

  for (int kt = 0; kt < 128; kt += PBK) {
    float4 av = make_float4(0.f, 0.f, 0.f, 0.f);
    if (n0 + lrow < NN)
      av = *(const float4*)&x[(size_t)(n0 + lrow) * 128 + kt + lk4];
    a_s[lk4 + 0][lrow] = av.x; a_s[lk4 + 1][lrow] = av.y;
    a_s[lk4 + 2][lrow] = av.z; a_s[lk4 + 3][lrow] = av.w;
#pragma unroll
    for (int i = 0; i < 4; ++i) {
      int k = lk0 + (i << 2);
      b_s[k][lc] = W[(kt + k) * 128 + cb + lc];
    }
    __syncthreads();
#pragma unroll
    for (int k = 0; k < PBK; ++k) {
      float4 a = *(const float4*)&a_s[k][ty << 2];
      float4 b = *(const float4*)&b_s[k][tx << 2];
      acc[0][0] = fmaf(a.x, b.x, acc[0][0]); acc[0][1] = fmaf(a.x, b.y, acc[0][1]);
      acc[0][2] = fmaf(a.x, b.z, acc[0][2]); acc[0][3] = fmaf(a.x, b.w, acc[0][3]);
      acc[1][0] = fmaf(a.y, b.x, acc[1][0]); acc[1][1] = fmaf(a.y, b.y, acc[1][1]);
      acc[1][2] = fmaf(a.y, b.z, acc[1][2]); acc[1][3] = fmaf(a.y, b.w, acc[1][3]);
      acc[2][0] = fmaf(a.z, b.x, acc[2][0]); acc[2][1] = fmaf(a.z, b.y, acc[2][1]);
      acc[2][2] = fmaf(a.z, b.z, acc[2][2]); acc[2][3] = fmaf(a.z, b.w, acc[2][3]);
      acc[3][0] = fmaf(a.w, b.x, acc[3][0]); acc[3][1] = fmaf(a.w, b.y, acc[3][1]);
      acc[3][2] = fmaf(a.w, b.z, acc[3][2]); acc[3][3] = fmaf(a.w, b.w, acc[3][3]);
    }
    __syncthreads();
  }

  float4 bb = *(const float4*)&bias[cb + (tx << 2)];
#pragma unroll
  for (int r = 0; r < 4; ++r) {
    int row = n0 + (ty << 2) + r;
    if (row < NN) {
      float4 o = make_float4(acc[r][0] + bb.x, acc[r][1] + bb.y,
                             acc[r][2] + bb.z, acc[r][3] + bb.w);
      *(float4*)&dst[(size_t)row * 128 + cb + (tx << 2)] = o;
    }
  }
}

// ---------------- CSR build ----------------
__global__ void k_deg(const int* __restrict__ ei, int* __restrict__ deg) {
  int e = blockIdx.x * 256 + threadIdx.x;
  if (e < NE) atomicAdd(&deg[ei[NE + e]], 1);
}

__global__ __launch_bounds__(1024) void k_scan(const int* __restrict__ deg,
                                               int* __restrict__ off) {
  __shared__ int s[1024];
  int carry = 0;
  for (int base = 0; base < NN; base += 1024) {
    int i = base + threadIdx.x;
    int v = (i < NN) ? deg[i] : 0;
    s[threadIdx.x] = v;
    __syncthreads();
    for (int o = 1; o < 1024; o <<= 1) {
      int t = 0;
      if (threadIdx.x >= o) t = s[threadIdx.x - o];
      __syncthreads();
      if (threadIdx.x >= o) s[threadIdx.x] += t;
      __syncthreads();
    }
    int incl = s[threadIdx.x];
    if (i < NN) off[i] = carry + incl - v;   // exclusive
    int tot = s[1023];
    __syncthreads();
    carry += tot;
  }
  if (threadIdx.x == 0) off[NN] = carry;
}

__global__ void k_fill(const int* __restrict__ ei, const int* __restrict__ off,
                       int* __restrict__ cur, int* __restrict__ elist) {
  int e = blockIdx.x * 256 + threadIdx.x;
  if (e < NE) {
    int d = ei[NE + e];
    int p = atomicAdd(&cur[d], 1);
    elist[off[d] + p] = e;
  }
}

// ---------------- fused attention + epilogue: one wave per dst node ---------
__global__ __launch_bounds__(256, 3) void k_main(
    const float* __restrict__ Q, const float* __restrict__ K2,
    const float* __restrict__ V2, const float* __restrict__ S2,
    const float* __restrict__ Wt, const float* __restrict__ bt,
    const float* __restrict__ We,
    const float* __restrict__ gamma, const float* __restrict__ beta,
    const float* __restrict__ msg, const int* __restrict__ last_update,
    const int* __restrict__ ei, const int* __restrict__ tt,
    const int* __restrict__ off, const int* __restrict__ elist,
    float* __restrict__ out)
{
  __shared__ unsigned We_s[EDIM * 64];      // bf16x2 packed (ch 2l | 2l+1)
  __shared__ float Wt_s[TDIM], bt_s[TDIM];
  __shared__ float attr_s[4][16][104];      // per-wave, 16-edge batch

  for (int i = threadIdx.x; i < EDIM * 64; i += 256) {
    float2 w = ((const float2*)We)[i];
    unsigned ua = __float_as_uint(w.x), ub = __float_as_uint(w.y);
    unsigned ra = (ua + 0x7FFFu + ((ua >> 16) & 1u)) >> 16;            // RNE bf16
    unsigned rb = (ub + 0x7FFFu + ((ub >> 16) & 1u)) & 0xFFFF0000u;
    We_s[i] = (ra & 0xFFFFu) | rb;
  }
  if (threadIdx.x < TDIM) { Wt_s[threadIdx.x] = Wt[threadIdx.x]; bt_s[threadIdx.x] = bt[threadIdx.x]; }
  __syncthreads();

  const int wid = threadIdx.x >> 6, lane = threadIdx.x & 63;
  const int node = blockIdx.x * 4 + wid;
  if (node >= NN) return;

  const int o0 = off[node];
  const int deg = off[node + 1] - o0;
  float2 q = ((const float2*)Q)[node * 64 + lane];   // channels 2l, 2l+1
  float m = -INFINITY, l = 0.f, acc0 = 0.f, acc1 = 0.f;
  float (*attrw)[104] = attr_s[wid];

  for (int cb = 0; cb < deg; cb += 16) {
    int cnt = deg - cb; if (cnt > 16) cnt = 16;

    float rel = 0.f, mg = 0.f; int srcl = 0;
    if (lane < cnt) {
      int eid = elist[o0 + cb + lane];
      srcl = ei[eid];
      mg = msg[eid];
      rel = (float)(last_update[srcl] - tt[eid]);
    }

#pragma unroll
    for (int ed = 0; ed < 16; ++ed) {
      if (ed < cnt) {
        float rel_e = __shfl(rel, ed);
        float mg_e  = __shfl(mg, ed);
        attrw[ed][lane] = ref_cosf(__fmaf_rn(rel_e, Wt_s[lane], bt_s[lane]));
        int j2 = 64 + lane;
        if (j2 < TDIM)       attrw[ed][j2]   = ref_cosf(__fmaf_rn(rel_e, Wt_s[j2], bt_s[j2]));
        else if (j2 == TDIM) attrw[ed][TDIM] = mg_e;
      }
    }
    asm volatile("s_waitcnt lgkmcnt(0)" ::: "memory");

    // e = edge_attr @ We for 16 edges, channels (2l, 2l+1) per lane
    float e0[16], e1[16];
#pragma unroll
    for (int ed = 0; ed < 16; ++ed) { e0[ed] = 0.f; e1[ed] = 0.f; }
    for (int j4 = 0; j4 < TDIM; j4 += 4) {
      unsigned w0 = We_s[(j4 + 0) * 64 + lane];
      unsigned w1 = We_s[(j4 + 1) * 64 + lane];
      unsigned w2 = We_s[(j4 + 2) * 64 + lane];
      unsigned w3 = We_s[(j4 + 3) * 64 + lane];
      float w0x = __uint_as_float(w0 << 16), w0y = __uint_as_float(w0 & 0xFFFF0000u);
      float w1x = __uint_as_float(w1 << 16), w1y = __uint_as_float(w1 & 0xFFFF0000u);
      float w2x = __uint_as_float(w2 << 16), w2y = __uint_as_float(w2 & 0xFFFF0000u);
      float w3x = __uint_as_float(w3 << 16), w3y = __uint_as_float(w3 & 0xFFFF0000u);
#pragma unroll
      for (int ed = 0; ed < 16; ++ed) {
        float4 a = *(const float4*)&attrw[ed][j4];
        e0[ed] = fmaf(a.x, w0x, e0[ed]); e1[ed] = fmaf(a.x, w0y, e1[ed]);
        e0[ed] = fmaf(a.y, w1x, e0[ed]); e1[ed] = fmaf(a.y, w1y, e1[ed]);
        e0[ed] = fmaf(a.z, w2x, e0[ed]); e1[ed] = fmaf(a.z, w2y, e1[ed]);
        e0[ed] = fmaf(a.w, w3x, e0[ed]); e1[ed] = fmaf(a.w, w3y, e1[ed]);
      }
    }
    {   // j = 100 (raw message channel)
      unsigned w = We_s[TDIM * 64 + lane];
      float wx = __uint_as_float(w << 16), wy = __uint_as_float(w & 0xFFFF0000u);
#pragma unroll
      for (int ed = 0; ed < 16; ++ed) {
        float a = attrw[ed][TDIM];
        e0[ed] = fmaf(a, wx, e0[ed]); e1[ed] = fmaf(a, wy, e1[ed]);
      }
    }

    float al[16], vx0[16], vy0[16];
#pragma unroll
    for (int ed = 0; ed < 16; ++ed) {
      if (ed < cnt) {
        int se = __shfl(srcl, ed);
        float2 kk = ((const float2*)K2)[se * 64 + lane];
        float kj0 = kk.x + e0[ed], kj1 = kk.y + e1[ed];
        float p = q.x * kj0 + q.y * kj1;
        p += __shfl_xor(p, 1); p += __shfl_xor(p, 2);
        p += __shfl_xor(p, 4); p += __shfl_xor(p, 8);   // 16-lane head reduce
        al[ed] = p * 0.17677669529663689f;               // 1/sqrt(32)
        float2 vv = ((const float2*)V2)[se * 64 + lane];
        vx0[ed] = vv.x + e0[ed]; vy0[ed] = vv.y + e1[ed];
      }
    }

    float cm = -INFINITY;
#pragma unroll
    for (int ed = 0; ed < 16; ++ed) if (ed < cnt) cm = fmaxf(cm, al[ed]);
    float nm = fmaxf(m, cm);
    float sc = __expf(m - nm);   // m=-inf -> 0
    l *= sc; acc0 *= sc; acc1 *= sc;
#pragma unroll
    for (int ed = 0; ed < 16; ++ed) {
      if (ed < cnt) {
        float w = __expf(al[ed] - nm);
        l += w;
        acc0 = fmaf(w, vx0[ed], acc0);
        acc1 = fmaf(w, vy0[ed], acc1);
      }
    }
    m = nm;
  }

  // epilogue: agg/den + skip, relu, layernorm (wave-wide over 128 channels)
  float inv = 1.f / (l + 1e-16f);
  float2 s2 = ((const float2*)S2)[node * 64 + lane];
  float r0 = fmaxf(fmaf(acc0, inv, s2.x), 0.f);
  float r1 = fmaxf(fmaf(acc1, inv, s2.y), 0.f);

  float sum = r0 + r1;
#pragma unroll
  for (int o = 1; o < 64; o <<= 1) sum += __shfl_xor(sum, o);
  float mu = sum * 0.0078125f;
  float d0 = r0 - mu, d1 = r1 - mu;
  float vs = d0 * d0 + d1 * d1;
#pragma unroll
  for (int o = 1; o < 64; o <<= 1) vs += __shfl_xor(vs, o);
  float rstd = rsqrtf(vs * 0.0078125f + 1e-5f);
  float2 g = ((const float2*)gamma)[lane], b = ((const float2*)beta)[lane];
  ((float2*)out)[node * 64 + lane] =
      make_float2(d0 * rstd * g.x + b.x, d1 * rstd * g.y + b.y);
}

// ---------------- launch ----------------
extern "C" void kernel_launch(void* const* d_in, const int* in_sizes, int n_in,
                              void* d_out, int out_size, void* d_ws, size_t ws_size,
                              hipStream_t stream)
{
  (void)in_sizes; (void)n_in; (void)out_size;
  if (ws_size < 106200064u) return;

  const float* x     = (const float*)d_in[0];
  const float* msg   = (const float*)d_in[1];
  const float* Wt    = (const float*)d_in[2];
  const float* bt    = (const float*)d_in[3];
  const float* Wq    = (const float*)d_in[4];
  const float* bq    = (const float*)d_in[5];
  const float* Wk    = (const float*)d_in[6];
  const float* bk    = (const float*)d_in[7];
  const float* Wv    = (const float*)d_in[8];
  const float* bv    = (const float*)d_in[9];
  const float* We    = (const float*)d_in[10];
  const float* Wskip = (const float*)d_in[11];
  const float* bskip = (const float*)d_in[12];
  const float* gamma = (const float*)d_in[13];
  const float* beta  = (const float*)d_in[14];
  const int* last_update = (const int*)d_in[15];
  const int* ei    = (const int*)d_in[16];
  const int* tt    = (const int*)d_in[17];

  char* ws = (char*)d_ws;
  float* Q    = (float*)(ws);
  float* K2   = (float*)(ws + 25600000);
  float* V2   = (float*)(ws + 51200000);
  float* S2   = (float*)(ws + 76800000);
  int* deg    = (int*)(ws + 102400000);
  int* cur    = (int*)(ws + 102600000);
  int* off    = (int*)(ws + 102800000);
  int* elist  = (int*)(ws + 103000064);

  hipMemsetAsync(deg, 0, 400000, stream);              // deg + cur (contiguous)
  k_deg <<<(NE + 255) / 256, 256, 0, stream>>>(ei, deg);
  k_scan<<<1, 1024, 0, stream>>>(deg, off);
  k_fill<<<(NE + 255) / 256, 256, 0, stream>>>(ei, off, cur, elist);
  dim3 pg(8, (NN + 63) / 64);
  k_proj<<<pg, 256, 0, stream>>>(x, Wq, bq, Wk, bk, Wv, bv,
                                 Wskip, bskip, Q, K2, V2, S2);
  k_main<<<(NN + 3) / 4, 256, 0, stream>>>(Q, K2, V2, S2, Wt, bt, We, gamma, beta,
                                           msg, last_update, ei, tt, off, elist,
                                           (float*)d_out);
}